// Round 12
// baseline (482.143 us; speedup 1.0000x reference)
//
#include <hip/hip_runtime.h>
#include <stdint.h>

#define NN 8192
#define FF 256
#define HH 64

typedef __attribute__((ext_vector_type(8))) short bf16x8;
typedef __attribute__((ext_vector_type(4))) float f32x4;

__device__ __forceinline__ uint16_t f2bf(float f) {
  union { float f; uint32_t i; } c; c.f = f;
  uint32_t r = c.i + 0x7FFFu + ((c.i >> 16) & 1u);
  return (uint16_t)(r >> 16);
}

// ---------------------------------------------------------------------------
// K0 v2: vectorized adj bit-pack. Thread packs 64 consecutive ints via
// 16 x int4 loads (wave: 16 KB contiguous, fill-like streaming) -> 1 uint64.
// bit k of maskp[w] = (adj[64w+k] != 0)  — same layout as R9 (verified).
// 8192 % 64 == 0 so chunks never straddle rows. grid = 4096 x 256, 1 iter.
// ---------------------------------------------------------------------------
__global__ __launch_bounds__(256) void k0_pack(
    const int* __restrict__ adj, unsigned long long* __restrict__ maskp) {
  const size_t tid = (size_t)blockIdx.x * 256 + threadIdx.x;
  const int* p = adj + tid * 64;
  unsigned long long word = 0;
#pragma unroll
  for (int j = 0; j < 16; ++j) {
    int4 a = *(const int4*)(p + j * 4);
    unsigned long long nib =
        (unsigned long long)((a.x != 0) | ((a.y != 0) << 1) |
                             ((a.z != 0) << 2) | ((a.w != 0) << 3));
    word |= nib << (4 * j);
  }
  maskp[tid] = word;
}

// ---------------------------------------------------------------------------
// K1: verified GEMM core, 512-wide (passed R11). Linear hT layout (matches
// k2's hrow indexing). Unchanged from R11.
// ---------------------------------------------------------------------------
__global__ __launch_bounds__(512) void k1_h(
    const float* __restrict__ x, const float* __restrict__ Wt,
    const float* __restrict__ bt, uint16_t* __restrict__ hT) {
  __shared__ float wtT[256 * 65];
  __shared__ float sbt[64];
  __shared__ uint16_t s_tr[64][34];
  const int t = threadIdx.x;
  const int lane = t & 63;
  const int w = t >> 6;            // 0..7

  if (t < 256) {
    for (int i = 0; i < 64; ++i)
      wtT[t * 65 + i] = Wt[(size_t)i * FF + t];
    if (t < 64) sbt[t] = bt[t];
  }
  __syncthreads();

  const int n0 = blockIdx.x * 32;
  const int r0 = n0 + w * 4;       // 4 rows per wave
  const float binit = sbt[lane];
  float acc[4];
#pragma unroll
  for (int r = 0; r < 4; ++r) acc[r] = binit;

  for (int f4 = 0; f4 < FF; f4 += 4) {
    float4 xs[4];
#pragma unroll
    for (int r = 0; r < 4; ++r)
      xs[r] = *(const float4*)(x + (size_t)(r0 + r) * FF + f4);
    const float wt0 = wtT[(f4 + 0) * 65 + lane];
    const float wt1 = wtT[(f4 + 1) * 65 + lane];
    const float wt2 = wtT[(f4 + 2) * 65 + lane];
    const float wt3 = wtT[(f4 + 3) * 65 + lane];
#pragma unroll
    for (int r = 0; r < 4; ++r)
      acc[r] += xs[r].x * wt0 + xs[r].y * wt1 + xs[r].z * wt2 + xs[r].w * wt3;
  }

#pragma unroll
  for (int r = 0; r < 4; ++r)
    s_tr[lane][w * 4 + r] = f2bf(acc[r]);
  __syncthreads();
#pragma unroll
  for (int i = 0; i < 2; ++i) {
    int idx = i * 512 + t;
    int c = idx >> 4;
    int d = idx & 15;
    uint32_t v = (uint32_t)s_tr[c][2 * d] | ((uint32_t)s_tr[c][2 * d + 1] << 16);
    *(uint32_t*)(hT + (size_t)c * NN + n0 + 2 * d) = v;
  }
}

// ---------------------------------------------------------------------------
// K2: R9 VERBATIM (passed). Bitmask A-frags, NO LDS staging, NO main-loop
// barriers, split-K 2 (grid 1024), verified MFMA/acc/reduce maps,
// deg-via-MFMA. This time paired with a FAST k0, so the total cleanly
// discriminates adj-rate theory (A: ~400us) vs k2-invariant mystery (B: ~480).
// ---------------------------------------------------------------------------
__global__ __launch_bounds__(256, 4) void k2_attn(
    const unsigned long long* __restrict__ maskp,
    const uint16_t* __restrict__ hT,
    float* __restrict__ nb_part, float* __restrict__ deg_part) {
  __shared__ float s_part[4][16][64];                    // 16 KB
  __shared__ float s_degw[4][16];

  const int t    = threadIdx.x;
  const int w    = t >> 6;
  const int lane = t & 63;
  const int m    = lane & 15;
  const int q    = lane >> 4;
  const int g    = blockIdx.x >> 1;
  const int half = blockIdx.x & 1;
  const int row0 = g * 16;

  bf16x8 vone;
#pragma unroll
  for (int j = 0; j < 8; ++j) vone[j] = (short)0x3F80;

  f32x4 acc0 = 0, acc1 = 0, acc2 = 0, acc3 = 0, accd = 0;
  const uint16_t* __restrict__ hrow = hT + (size_t)m * NN;
  const unsigned long long* __restrict__ mrow = maskp + (size_t)(row0 + m) * (NN / 64);
  const int base = half * (NN / 2);
  const int qs = q * 8;

  for (int tile = 0; tile < 8; ++tile) {
    const int c0 = base + tile * 512;
#pragma unroll
    for (int it = 0; it < 2; ++it) {
      const int kl = w * 128 + it * 64;
      const int k0 = c0 + kl + qs;
      const int k1 = k0 + 32;
      // ---- A-fragments from mask bits (R9 verbatim, passed) ----
      uint2 mw = *(const uint2*)(mrow + ((c0 + kl) >> 6));
      uint32_t bA = (mw.x >> qs) & 0xFFu;
      uint32_t bB = (mw.y >> qs) & 0xFFu;
      union U { bf16x8 v; uint32_t u[4]; } afA, afB;
#pragma unroll
      for (int i = 0; i < 4; ++i) {
        afA.u[i] = (((bA >> (2 * i)) & 1u) |
                    (((bA >> (2 * i + 1)) & 1u) << 16)) * 0x3F80u;
        afB.u[i] = (((bB >> (2 * i)) & 1u) |
                    (((bB >> (2 * i + 1)) & 1u) << 16)) * 0x3F80u;
      }
      // ---- B-fragments (hT) + 10 MFMA: verbatim verified body ----
      bf16x8 b0 = *(const bf16x8*)(hrow + k0);
      bf16x8 b1 = *(const bf16x8*)(hrow + 16 * NN + k0);
      bf16x8 b2 = *(const bf16x8*)(hrow + 32 * NN + k0);
      bf16x8 b3 = *(const bf16x8*)(hrow + 48 * NN + k0);
      bf16x8 d0 = *(const bf16x8*)(hrow + k1);
      bf16x8 d1 = *(const bf16x8*)(hrow + 16 * NN + k1);
      bf16x8 d2 = *(const bf16x8*)(hrow + 32 * NN + k1);
      bf16x8 d3 = *(const bf16x8*)(hrow + 48 * NN + k1);
      acc0 = __builtin_amdgcn_mfma_f32_16x16x32_bf16(afA.v, b0, acc0, 0, 0, 0);
      acc1 = __builtin_amdgcn_mfma_f32_16x16x32_bf16(afA.v, b1, acc1, 0, 0, 0);
      acc2 = __builtin_amdgcn_mfma_f32_16x16x32_bf16(afA.v, b2, acc2, 0, 0, 0);
      acc3 = __builtin_amdgcn_mfma_f32_16x16x32_bf16(afA.v, b3, acc3, 0, 0, 0);
      accd = __builtin_amdgcn_mfma_f32_16x16x32_bf16(afA.v, vone, accd, 0, 0, 0);
      acc0 = __builtin_amdgcn_mfma_f32_16x16x32_bf16(afB.v, d0, acc0, 0, 0, 0);
      acc1 = __builtin_amdgcn_mfma_f32_16x16x32_bf16(afB.v, d1, acc1, 0, 0, 0);
      acc2 = __builtin_amdgcn_mfma_f32_16x16x32_bf16(afB.v, d2, acc2, 0, 0, 0);
      acc3 = __builtin_amdgcn_mfma_f32_16x16x32_bf16(afB.v, d3, acc3, 0, 0, 0);
      accd = __builtin_amdgcn_mfma_f32_16x16x32_bf16(afB.v, vone, accd, 0, 0, 0);
    }
  }

  // ---- acc -> s_part (verified verbatim map) + deg-via-MFMA (verbatim) ----
#pragma unroll
  for (int rg = 0; rg < 4; ++rg) {
    s_part[w][q * 4 + rg][ 0 + m] = acc0[rg];
    s_part[w][q * 4 + rg][16 + m] = acc1[rg];
    s_part[w][q * 4 + rg][32 + m] = acc2[rg];
    s_part[w][q * 4 + rg][48 + m] = acc3[rg];
  }
  if (m == 0) {
#pragma unroll
    for (int rg = 0; rg < 4; ++rg) s_degw[w][q * 4 + rg] = accd[rg];
  }
  __syncthreads();

  // ---- cross-wave reduce -> this half's disjoint partial buffers ----
  float* __restrict__ dst = nb_part + ((size_t)half * NN + row0) * HH;
  for (int idx = t; idx < 16 * 64; idx += 256) {
    int r = idx >> 6, c = idx & 63;
    float s = s_part[0][r][c] + s_part[1][r][c] +
              s_part[2][r][c] + s_part[3][r][c];
    dst[(size_t)r * HH + c] = s;
  }
  if (t < 16) {
    float d = s_degw[0][t] + s_degw[1][t] + s_degw[2][t] + s_degw[3][t];
    deg_part[half * NN + row0 + t] = d;
  }
}

// ---------------------------------------------------------------------------
// K3: epilogue, verified maps (passed R6..R11). Unchanged.
// ---------------------------------------------------------------------------
__global__ __launch_bounds__(256) void k3_epi(
    const float* __restrict__ x, const float* __restrict__ nb_part,
    const float* __restrict__ deg_part, const float* __restrict__ Wp,
    const float* __restrict__ bp, const float* __restrict__ gamma,
    const float* __restrict__ beta, float* __restrict__ out) {
  __shared__ float s_nb[16][64];
  __shared__ float s_y[16 * 256];

  const int t    = threadIdx.x;
  const int w    = t >> 6;
  const int lane = t & 63;
  const int row0 = blockIdx.x * 16;

  for (int idx = t; idx < 16 * 64; idx += 256) {
    int r = idx >> 6, c = idx & 63;
    float d = deg_part[row0 + r] + deg_part[NN + row0 + r];
    float s = nb_part[(size_t)(row0 + r) * HH + c] +
              nb_part[(size_t)(NN + row0 + r) * HH + c];
    s_nb[r][c] = (d > 0.5f) ? s / d : 0.f;
  }
  __syncthreads();

  {
    const int f = t;
    float wp[64];
    const float* wrow = Wp + (size_t)f * HH;
#pragma unroll
    for (int j = 0; j < 16; ++j) {
      float4 v = *(const float4*)(wrow + j * 4);
      wp[j * 4 + 0] = v.x; wp[j * 4 + 1] = v.y;
      wp[j * 4 + 2] = v.z; wp[j * 4 + 3] = v.w;
    }
    const float bpf = bp[f];
    for (int r = 0; r < 16; ++r) {
      float a = bpf;
#pragma unroll
      for (int k = 0; k < 64; k += 4) {
        float4 nv = *(const float4*)&s_nb[r][k];
        a += nv.x * wp[k] + nv.y * wp[k + 1] + nv.z * wp[k + 2] + nv.w * wp[k + 3];
      }
      float y = x[(size_t)(row0 + r) * FF + f] + a;
      s_y[r * 256 + f] = y;
    }
  }
  __syncthreads();

  for (int i = 0; i < 4; ++i) {
    const int r = w * 4 + i;
    float4 v = *(const float4*)&s_y[r * 256 + lane * 4];
    float sum = v.x + v.y + v.z + v.w;
    float ss  = v.x * v.x + v.y * v.y + v.z * v.z + v.w * v.w;
#pragma unroll
    for (int o = 32; o >= 1; o >>= 1) {
      sum += __shfl_xor(sum, o, 64);
      ss  += __shfl_xor(ss, o, 64);
    }
    const float mu  = sum * (1.0f / 256.0f);
    const float var = ss * (1.0f / 256.0f) - mu * mu;
    const float rs  = rsqrtf(var + 1e-5f);
    const int f0 = lane * 4;
    float4 g = *(const float4*)(gamma + f0);
    float4 b = *(const float4*)(beta + f0);
    float4 o4;
    o4.x = g.x * (v.x - mu) * rs + b.x;
    o4.y = g.y * (v.y - mu) * rs + b.y;
    o4.z = g.z * (v.z - mu) * rs + b.z;
    o4.w = g.w * (v.w - mu) * rs + b.w;
    *(float4*)(out + (size_t)(row0 + r) * FF + f0) = o4;
  }
}

extern "C" void kernel_launch(void* const* d_in, const int* in_sizes, int n_in,
                              void* d_out, int out_size, void* d_ws, size_t ws_size,
                              hipStream_t stream) {
  const float* x     = (const float*)d_in[0];
  const int*   adj   = (const int*)d_in[1];
  const float* Wt    = (const float*)d_in[2];
  const float* bt    = (const float*)d_in[3];
  // d_in[4] = Wa, d_in[5] = ba: provably dead (softmax scores are row-constant)
  const float* Wp    = (const float*)d_in[6];
  const float* bp    = (const float*)d_in[7];
  const float* gamma = (const float*)d_in[8];
  const float* beta  = (const float*)d_in[9];
  float* out = (float*)d_out;

  // ws: hT 1MB | nb_part 4MB | deg_part 64KB | maskp 8MB
  uint16_t*           hT       = (uint16_t*)d_ws;
  float*              nb_part  = (float*)((char*)d_ws + (1u << 20));
  float*              deg_part = (float*)((char*)d_ws + (5u << 20));
  unsigned long long* maskp    = (unsigned long long*)((char*)d_ws + (6u << 20));

  k0_pack<<<4096, 256, 0, stream>>>(adj, maskp);
  k1_h   <<<256,  512, 0, stream>>>(x, Wt, bt, hT);
  k2_attn<<<1024, 256, 0, stream>>>(maskp, hT, nb_part, deg_part);
  k3_epi <<<512,  256, 0, stream>>>(x, nb_part, deg_part, Wp, bp, gamma, beta, out);
}

// Round 13
// 435.849 us; speedup vs baseline: 1.1062x; 1.1062x over previous
//
#include <hip/hip_runtime.h>
#include <stdint.h>

#define NN 8192
#define FF 256
#define HH 64

typedef __attribute__((ext_vector_type(8))) short bf16x8;
typedef __attribute__((ext_vector_type(4))) float f32x4;

__device__ __forceinline__ uint16_t f2bf(float f) {
  union { float f; uint32_t i; } c; c.f = f;
  uint32_t r = c.i + 0x7FFFu + ((c.i >> 16) & 1u);
  return (uint16_t)(r >> 16);
}

// ---------------------------------------------------------------------------
// K1: verified GEMM core, 512-wide (passed R11, best total). Unchanged.
// grid = 256 x 32 rows.
// ---------------------------------------------------------------------------
__global__ __launch_bounds__(512) void k1_h(
    const float* __restrict__ x, const float* __restrict__ Wt,
    const float* __restrict__ bt, uint16_t* __restrict__ hT) {
  __shared__ float wtT[256 * 65];
  __shared__ float sbt[64];
  __shared__ uint16_t s_tr[64][34];
  const int t = threadIdx.x;
  const int lane = t & 63;
  const int w = t >> 6;            // 0..7

  if (t < 256) {
    for (int i = 0; i < 64; ++i)
      wtT[t * 65 + i] = Wt[(size_t)i * FF + t];
    if (t < 64) sbt[t] = bt[t];
  }
  __syncthreads();

  const int n0 = blockIdx.x * 32;
  const int r0 = n0 + w * 4;       // 4 rows per wave
  const float binit = sbt[lane];
  float acc[4];
#pragma unroll
  for (int r = 0; r < 4; ++r) acc[r] = binit;

  for (int f4 = 0; f4 < FF; f4 += 4) {
    float4 xs[4];
#pragma unroll
    for (int r = 0; r < 4; ++r)
      xs[r] = *(const float4*)(x + (size_t)(r0 + r) * FF + f4);
    const float wt0 = wtT[(f4 + 0) * 65 + lane];
    const float wt1 = wtT[(f4 + 1) * 65 + lane];
    const float wt2 = wtT[(f4 + 2) * 65 + lane];
    const float wt3 = wtT[(f4 + 3) * 65 + lane];
#pragma unroll
    for (int r = 0; r < 4; ++r)
      acc[r] += xs[r].x * wt0 + xs[r].y * wt1 + xs[r].z * wt2 + xs[r].w * wt3;
  }

#pragma unroll
  for (int r = 0; r < 4; ++r)
    s_tr[lane][w * 4 + r] = f2bf(acc[r]);
  __syncthreads();
#pragma unroll
  for (int i = 0; i < 2; ++i) {
    int idx = i * 512 + t;
    int c = idx >> 4;
    int d = idx & 15;
    uint32_t v = (uint32_t)s_tr[c][2 * d] | ((uint32_t)s_tr[c][2 * d + 1] << 16);
    *(uint32_t*)(hT + (size_t)c * NN + n0 + 2 * d) = v;
  }
}

// ---------------------------------------------------------------------------
// K2: R6 VERBATIM (the verified best-total kernel, passed R6/R11).
// Block-wide barriered LDS staging, 512-col swizzled tile, split-K 2
// (grid 1024), deg-via-MFMA, verified MFMA/acc/reduce maps.
// ---------------------------------------------------------------------------
__global__ __launch_bounds__(256) void k2_attn(
    const int* __restrict__ adj, const uint16_t* __restrict__ hT,
    float* __restrict__ nb_part, float* __restrict__ deg_part) {
  __shared__ __align__(16) unsigned char af[16 * 1024];  // 16 rows x 1 KB
  __shared__ float s_part[4][16][64];                    // 16 KB
  __shared__ float s_degw[4][16];

  const int t    = threadIdx.x;
  const int w    = t >> 6;
  const int lane = t & 63;
  const int m    = lane & 15;
  const int q    = lane >> 4;
  const int g    = blockIdx.x >> 1;
  const int half = blockIdx.x & 1;
  const int row0 = g * 16;
  const int rsw  = (m & 7) << 4;

  bf16x8 vone;
#pragma unroll
  for (int j = 0; j < 8; ++j) vone[j] = (short)0x3F80;

  f32x4 acc0 = 0, acc1 = 0, acc2 = 0, acc3 = 0, accd = 0;
  const uint16_t* __restrict__ hrow = hT + (size_t)m * NN;
  const int sr = t >> 7;      // 0/1: which row of the pair this thread stages
  const int sc = t & 127;     // int4 group within the 512-col row

  const int base = half * (NN / 2);
  for (int tile = 0; tile < 8; ++tile) {
    const int c0 = base + tile * 512;
    // ---- stage: instr i covers rows {2i, 2i+1}; 2 KB contiguous per row ----
#pragma unroll
    for (int i = 0; i < 8; ++i) {
      const int r_ = 2 * i + sr;
      int4 a = *(const int4*)(adj + (size_t)(row0 + r_) * NN + c0 + sc * 4);
      uint32_t lo = ((uint32_t)a.x | ((uint32_t)a.y << 16)) * 0x3F80u;
      uint32_t hi = ((uint32_t)a.z | ((uint32_t)a.w << 16)) * 0x3F80u;
      uint2 w2; w2.x = lo; w2.y = hi;
      *(uint2*)(af + r_ * 1024 + (((uint32_t)(sc * 8)) ^ ((r_ & 7) << 4))) = w2;
    }
    __syncthreads();
    // ---- compute: wave w owns cols [w*128, w*128+128) of the tile ----
#pragma unroll
    for (int it = 0; it < 2; ++it) {
      const int kl = w * 128 + it * 64;
      const int k0 = c0 + kl + q * 8;
      const int k1 = k0 + 32;
      bf16x8 afA = *(const bf16x8*)(af + m * 1024 +
                                    (((uint32_t)((kl + q * 8) * 2)) ^ rsw));
      bf16x8 afB = *(const bf16x8*)(af + m * 1024 +
                                    (((uint32_t)((kl + q * 8) * 2 + 64)) ^ rsw));
      bf16x8 b0 = *(const bf16x8*)(hrow + k0);
      bf16x8 b1 = *(const bf16x8*)(hrow + 16 * NN + k0);
      bf16x8 b2 = *(const bf16x8*)(hrow + 32 * NN + k0);
      bf16x8 b3 = *(const bf16x8*)(hrow + 48 * NN + k0);
      bf16x8 d0 = *(const bf16x8*)(hrow + k1);
      bf16x8 d1 = *(const bf16x8*)(hrow + 16 * NN + k1);
      bf16x8 d2 = *(const bf16x8*)(hrow + 32 * NN + k1);
      bf16x8 d3 = *(const bf16x8*)(hrow + 48 * NN + k1);
      acc0 = __builtin_amdgcn_mfma_f32_16x16x32_bf16(afA, b0, acc0, 0, 0, 0);
      acc1 = __builtin_amdgcn_mfma_f32_16x16x32_bf16(afA, b1, acc1, 0, 0, 0);
      acc2 = __builtin_amdgcn_mfma_f32_16x16x32_bf16(afA, b2, acc2, 0, 0, 0);
      acc3 = __builtin_amdgcn_mfma_f32_16x16x32_bf16(afA, b3, acc3, 0, 0, 0);
      accd = __builtin_amdgcn_mfma_f32_16x16x32_bf16(afA, vone, accd, 0, 0, 0);
      acc0 = __builtin_amdgcn_mfma_f32_16x16x32_bf16(afB, d0, acc0, 0, 0, 0);
      acc1 = __builtin_amdgcn_mfma_f32_16x16x32_bf16(afB, d1, acc1, 0, 0, 0);
      acc2 = __builtin_amdgcn_mfma_f32_16x16x32_bf16(afB, d2, acc2, 0, 0, 0);
      acc3 = __builtin_amdgcn_mfma_f32_16x16x32_bf16(afB, d3, acc3, 0, 0, 0);
      accd = __builtin_amdgcn_mfma_f32_16x16x32_bf16(afB, vone, accd, 0, 0, 0);
    }
    __syncthreads();
  }

  // ---- acc -> s_part (verified verbatim map) + deg-via-MFMA (verbatim) ----
#pragma unroll
  for (int rg = 0; rg < 4; ++rg) {
    s_part[w][q * 4 + rg][ 0 + m] = acc0[rg];
    s_part[w][q * 4 + rg][16 + m] = acc1[rg];
    s_part[w][q * 4 + rg][32 + m] = acc2[rg];
    s_part[w][q * 4 + rg][48 + m] = acc3[rg];
  }
  if (m == 0) {
#pragma unroll
    for (int rg = 0; rg < 4; ++rg) s_degw[w][q * 4 + rg] = accd[rg];
  }
  __syncthreads();

  // ---- cross-wave reduce -> this half's disjoint partial buffers ----
  float* __restrict__ dst = nb_part + ((size_t)half * NN + row0) * HH;
  for (int idx = t; idx < 16 * 64; idx += 256) {
    int r = idx >> 6, c = idx & 63;
    float s = s_part[0][r][c] + s_part[1][r][c] +
              s_part[2][r][c] + s_part[3][r][c];
    dst[(size_t)r * HH + c] = s;
  }
  if (t < 16) {
    float d = s_degw[0][t] + s_degw[1][t] + s_degw[2][t] + s_degw[3][t];
    deg_part[half * NN + row0 + t] = d;
  }
}

// ---------------------------------------------------------------------------
// K3: epilogue, verified maps (passed R6..R12). Unchanged.
// ---------------------------------------------------------------------------
__global__ __launch_bounds__(256) void k3_epi(
    const float* __restrict__ x, const float* __restrict__ nb_part,
    const float* __restrict__ deg_part, const float* __restrict__ Wp,
    const float* __restrict__ bp, const float* __restrict__ gamma,
    const float* __restrict__ beta, float* __restrict__ out) {
  __shared__ float s_nb[16][64];
  __shared__ float s_y[16 * 256];

  const int t    = threadIdx.x;
  const int w    = t >> 6;
  const int lane = t & 63;
  const int row0 = blockIdx.x * 16;

  for (int idx = t; idx < 16 * 64; idx += 256) {
    int r = idx >> 6, c = idx & 63;
    float d = deg_part[row0 + r] + deg_part[NN + row0 + r];
    float s = nb_part[(size_t)(row0 + r) * HH + c] +
              nb_part[(size_t)(NN + row0 + r) * HH + c];
    s_nb[r][c] = (d > 0.5f) ? s / d : 0.f;
  }
  __syncthreads();

  {
    const int f = t;
    float wp[64];
    const float* wrow = Wp + (size_t)f * HH;
#pragma unroll
    for (int j = 0; j < 16; ++j) {
      float4 v = *(const float4*)(wrow + j * 4);
      wp[j * 4 + 0] = v.x; wp[j * 4 + 1] = v.y;
      wp[j * 4 + 2] = v.z; wp[j * 4 + 3] = v.w;
    }
    const float bpf = bp[f];
    for (int r = 0; r < 16; ++r) {
      float a = bpf;
#pragma unroll
      for (int k = 0; k < 64; k += 4) {
        float4 nv = *(const float4*)&s_nb[r][k];
        a += nv.x * wp[k] + nv.y * wp[k + 1] + nv.z * wp[k + 2] + nv.w * wp[k + 3];
      }
      float y = x[(size_t)(row0 + r) * FF + f] + a;
      s_y[r * 256 + f] = y;
    }
  }
  __syncthreads();

  for (int i = 0; i < 4; ++i) {
    const int r = w * 4 + i;
    float4 v = *(const float4*)&s_y[r * 256 + lane * 4];
    float sum = v.x + v.y + v.z + v.w;
    float ss  = v.x * v.x + v.y * v.y + v.z * v.z + v.w * v.w;
#pragma unroll
    for (int o = 32; o >= 1; o >>= 1) {
      sum += __shfl_xor(sum, o, 64);
      ss  += __shfl_xor(ss, o, 64);
    }
    const float mu  = sum * (1.0f / 256.0f);
    const float var = ss * (1.0f / 256.0f) - mu * mu;
    const float rs  = rsqrtf(var + 1e-5f);
    const int f0 = lane * 4;
    float4 g = *(const float4*)(gamma + f0);
    float4 b = *(const float4*)(beta + f0);
    float4 o4;
    o4.x = g.x * (v.x - mu) * rs + b.x;
    o4.y = g.y * (v.y - mu) * rs + b.y;
    o4.z = g.z * (v.z - mu) * rs + b.z;
    o4.w = g.w * (v.w - mu) * rs + b.w;
    *(float4*)(out + (size_t)(row0 + r) * FF + f0) = o4;
  }
}

extern "C" void kernel_launch(void* const* d_in, const int* in_sizes, int n_in,
                              void* d_out, int out_size, void* d_ws, size_t ws_size,
                              hipStream_t stream) {
  const float* x     = (const float*)d_in[0];
  const int*   adj   = (const int*)d_in[1];
  const float* Wt    = (const float*)d_in[2];
  const float* bt    = (const float*)d_in[3];
  // d_in[4] = Wa, d_in[5] = ba: provably dead (softmax scores are row-constant)
  const float* Wp    = (const float*)d_in[6];
  const float* bp    = (const float*)d_in[7];
  const float* gamma = (const float*)d_in[8];
  const float* beta  = (const float*)d_in[9];
  float* out = (float*)d_out;

  // ws layout: hT 1 MB | nb_part 4 MB (two halves) | deg_part 64 KB (float)
  uint16_t* hT       = (uint16_t*)d_ws;
  float*    nb_part  = (float*)((char*)d_ws + (1u << 20));
  float*    deg_part = (float*)((char*)d_ws + (5u << 20));

  k1_h   <<<256,  512, 0, stream>>>(x, Wt, bt, hT);
  k2_attn<<<1024, 256, 0, stream>>>(adj, hT, nb_part, deg_part);
  k3_epi <<<512,  256, 0, stream>>>(x, nb_part, deg_part, Wp, bp, gamma, beta, out);
}